// Round 1
// baseline (623.650 us; speedup 1.0000x reference)
//
#include <hip/hip_runtime.h>
#include <hip/hip_bf16.h>

// Problem constants (B=16, S=100, D=8192, P=100, W=3)
constexpr int Dk   = 8192;
constexpr int Bb   = 16;
constexpr int Ss   = 100;
constexpr int Pp   = 100;
constexpr int MROW = Bb * (Ss + 2);   // 1632 padded rows
constexpr int NCOL = 3 * Pp;          // 300 output cols (q|k|v)
constexpr int ROWS = 32;              // rows per GEMM block
constexpr int KSPL = 16;              // K splits
constexpr int KCH  = Dk / KSPL;       // 512 K per block

__global__ void zero_ws(float* __restrict__ p, int n) {
    int i = blockIdx.x * blockDim.x + threadIdx.x;
    if (i < n) p[i] = 0.0f;
}

// One block: 32 padded rows x 300 cols, K-chunk of 512, atomicAdd partials.
// blockIdx.x in [0,50): interior rows (map straight into x).
// blockIdx.x == 50: the 32 pad rows (16 forward + 16 backward).
__global__ __launch_bounds__(320) void qkv_gemm(
    const float* __restrict__ x,  const float* __restrict__ wq,
    const float* __restrict__ wk, const float* __restrict__ wv,
    const float* __restrict__ fpad, const float* __restrict__ bpad,
    float* __restrict__ qkvp) {
    const int c = threadIdx.x;
    const bool active = c < NCOL;
    const float* wmat = (c < Pp) ? wq : ((c < 2 * Pp) ? wk : wv);
    const int col = (c < Pp) ? c : ((c < 2 * Pp) ? (c - Pp) : (c - 2 * Pp));

    const float* rp[ROWS];
    int orow[ROWS];
    if (blockIdx.x < 50) {
        const int j0 = blockIdx.x * ROWS;   // row index within x (0..1599)
        #pragma unroll
        for (int i = 0; i < ROWS; ++i) {
            const int j = j0 + i;
            rp[i]   = x + (size_t)j * Dk;
            orow[i] = (j / Ss) * (Ss + 2) + (j % Ss) + 1;  // padded row index
        }
    } else {
        #pragma unroll
        for (int i = 0; i < ROWS; ++i) {
            if (i < Bb) { rp[i] = fpad + (size_t)i * Dk;        orow[i] = i * (Ss + 2); }
            else        { rp[i] = bpad + (size_t)(i - Bb) * Dk; orow[i] = (i - Bb) * (Ss + 2) + Ss + 1; }
        }
    }

    float acc[ROWS];
    #pragma unroll
    for (int i = 0; i < ROWS; ++i) acc[i] = 0.0f;

    const int k0 = blockIdx.y * KCH;
    const float* wp = wmat + (size_t)k0 * Pp + col;

    for (int k = 0; k < KCH; k += 4) {
        float w0 = 0.f, w1 = 0.f, w2 = 0.f, w3 = 0.f;
        if (active) {
            w0 = wp[(size_t)(k + 0) * Pp];
            w1 = wp[(size_t)(k + 1) * Pp];
            w2 = wp[(size_t)(k + 2) * Pp];
            w3 = wp[(size_t)(k + 3) * Pp];
        }
        #pragma unroll
        for (int i = 0; i < ROWS; ++i) {
            // wave-uniform address -> scalar/broadcast load
            const float4 xv = *(const float4*)(rp[i] + k0 + k);
            acc[i] = fmaf(xv.x, w0, acc[i]);
            acc[i] = fmaf(xv.y, w1, acc[i]);
            acc[i] = fmaf(xv.z, w2, acc[i]);
            acc[i] = fmaf(xv.w, w3, acc[i]);
        }
    }

    if (active) {
        #pragma unroll
        for (int i = 0; i < ROWS; ++i)
            atomicAdd(&qkvp[(size_t)orow[i] * NCOL + c], acc[i]);
    }
}

// One block per (b,s): scores[1,u] = Q[s+1].K[s+u], softmax over u, out = sum attn_u * V[s+u]
__global__ __launch_bounds__(128) void attn_kernel(
    const float* __restrict__ qkvp, float* __restrict__ out) {
    const int bs = blockIdx.x;           // 0..1599
    const int b = bs / Ss, s = bs % Ss;
    __shared__ float q[Pp], kbuf[3][Pp], vbuf[3][Pp];
    __shared__ float sc[3];
    const int tid = threadIdx.x;
    const size_t base = (size_t)(b * (Ss + 2) + s) * NCOL;   // row (b, s)

    if (tid < Pp) {
        q[tid] = qkvp[base + NCOL + tid];                    // Q row s+1, col tid
        #pragma unroll
        for (int u = 0; u < 3; ++u) {
            kbuf[u][tid] = qkvp[base + (size_t)u * NCOL + Pp     + tid];
            vbuf[u][tid] = qkvp[base + (size_t)u * NCOL + 2 * Pp + tid];
        }
    }
    __syncthreads();

    if (tid < 64) {
        #pragma unroll
        for (int u = 0; u < 3; ++u) {
            float ps = 0.0f;
            for (int p = tid; p < Pp; p += 64) ps += q[p] * kbuf[u][p];
            #pragma unroll
            for (int off = 32; off > 0; off >>= 1) ps += __shfl_down(ps, off);
            if (tid == 0) sc[u] = ps;
        }
    }
    __syncthreads();

    const float m  = fmaxf(sc[0], fmaxf(sc[1], sc[2]));
    const float e0 = __expf(sc[0] - m), e1 = __expf(sc[1] - m), e2 = __expf(sc[2] - m);
    const float inv = 1.0f / (e0 + e1 + e2);

    if (tid < Pp) {
        out[(size_t)bs * Pp + tid] =
            inv * (e0 * vbuf[0][tid] + e1 * vbuf[1][tid] + e2 * vbuf[2][tid]);
    }
}

extern "C" void kernel_launch(void* const* d_in, const int* in_sizes, int n_in,
                              void* d_out, int out_size, void* d_ws, size_t ws_size,
                              hipStream_t stream) {
    const float* x    = (const float*)d_in[0];
    const float* wq   = (const float*)d_in[1];
    const float* wk   = (const float*)d_in[2];
    const float* wv   = (const float*)d_in[3];
    const float* fpad = (const float*)d_in[4];
    const float* bpad = (const float*)d_in[5];
    float* out  = (float*)d_out;
    float* qkvp = (float*)d_ws;                 // 1632*300 floats = 1.96 MB

    const int nqkv = MROW * NCOL;               // 489600
    zero_ws<<<(nqkv + 255) / 256, 256, 0, stream>>>(qkvp, nqkv);

    dim3 grid(51, KSPL);
    qkv_gemm<<<grid, 320, 0, stream>>>(x, wq, wk, wv, fpad, bpad, qkvp);

    attn_kernel<<<Bb * Ss, 128, 0, stream>>>(qkvp, out);
}

// Round 2
// 200.180 us; speedup vs baseline: 3.1155x; 3.1155x over previous
//
#include <hip/hip_runtime.h>
#include <hip/hip_bf16.h>

// B=16, S=100, D=8192, P=100, W=3
constexpr int Dk   = 8192;
constexpr int Bb   = 16;
constexpr int Ss   = 100;
constexpr int Pp   = 100;
constexpr int MROW = 1632;     // 16 * 102 padded rows
constexpr int NC   = 304;      // q(100) | k(100) | v(100) | 4 zero cols
constexpr int A_MT = 104;      // m-tiles of 16 -> 1664 rows (32 zero pad rows)
constexpr int B_NT = 24;       // n-tiles of 16 -> 384 cols (zeros past 303)
constexpr int KG   = 1024;     // k-groups of 8 (K=8192)

// packed fragment layout: [tile][kg][lane16][8] bf16, element index
//   ((tile*KG + kg)*16 + lane)*8
constexpr size_t A_SEG = (size_t)A_MT * KG * 128;  // shorts
constexpr size_t B_SEG = (size_t)B_NT * KG * 128;  // shorts

typedef short s8v  __attribute__((ext_vector_type(8)));
typedef float f4v  __attribute__((ext_vector_type(4)));

__device__ inline unsigned short f2bf_rne(float f) {
    unsigned u = __float_as_uint(f);
    u += 0x7fffu + ((u >> 16) & 1u);
    return (unsigned short)(u >> 16);
}

__global__ __launch_bounds__(256) void zero_ws(float* __restrict__ p, int n) {
    int i = blockIdx.x * blockDim.x + threadIdx.x;
    if (i < n) p[i] = 0.0f;
}

// Pack x (+pads) into A_hi/A_lo fragment layout. grid (104, 16), 256 thr.
__global__ __launch_bounds__(256) void pack_a(
    const float* __restrict__ x, const float* __restrict__ fpad,
    const float* __restrict__ bpad,
    short* __restrict__ a_hi, short* __restrict__ a_lo) {
    const int mt  = blockIdx.x;          // 0..103
    const int kc  = blockIdx.y;          // 0..15, 512 k each
    const int m   = threadIdx.x & 15;
    const int kgl = threadIdx.x >> 4;    // 0..15
    const int r   = mt * 16 + m;         // padded row

    const float* src = nullptr;
    if (r < MROW) {
        const int b = r / 102, rr = r % 102;
        if (rr == 0)        src = fpad + (size_t)b * Dk;
        else if (rr == 101) src = bpad + (size_t)b * Dk;
        else                src = x + ((size_t)b * Ss + rr - 1) * Dk;
    }

    for (int i = 0; i < 4; ++i) {
        const int kg = kc * 64 + i * 16 + kgl;
        const size_t doff = ((size_t)mt * KG + kg) * 128 + (size_t)m * 8;
        s8v hi, lo;
        if (src) {
            const float4* p4 = (const float4*)(src + (size_t)kg * 8);
            const float4 v0 = p4[0], v1 = p4[1];
            float vv[8] = {v0.x, v0.y, v0.z, v0.w, v1.x, v1.y, v1.z, v1.w};
            #pragma unroll
            for (int j = 0; j < 8; ++j) {
                const unsigned short hb = f2bf_rne(vv[j]);
                const float hf = __uint_as_float((unsigned)hb << 16);
                hi[j] = (short)hb;
                lo[j] = (short)f2bf_rne(vv[j] - hf);
            }
        } else {
            #pragma unroll
            for (int j = 0; j < 8; ++j) { hi[j] = 0; lo[j] = 0; }
        }
        *(s8v*)(a_hi + doff) = hi;
        *(s8v*)(a_lo + doff) = lo;
    }
}

// Pack [wq|wk|wv|0] into B_hi/B_lo fragment layout. 384*1024 threads.
__global__ __launch_bounds__(256) void pack_b(
    const float* __restrict__ wq, const float* __restrict__ wk,
    const float* __restrict__ wv,
    short* __restrict__ b_hi, short* __restrict__ b_lo) {
    const int id = blockIdx.x * 256 + threadIdx.x;
    const int n  = id % 384;
    const int kg = id / 384;
    if (kg >= KG) return;

    const float* w = nullptr; int p = 0;
    if (n < 100)      { w = wq; p = n; }
    else if (n < 200) { w = wk; p = n - 100; }
    else if (n < 300) { w = wv; p = n - 200; }

    s8v hi, lo;
    #pragma unroll
    for (int j = 0; j < 8; ++j) {
        float v = w ? w[(size_t)(kg * 8 + j) * Pp + p] : 0.0f;
        const unsigned short hb = f2bf_rne(v);
        const float hf = __uint_as_float((unsigned)hb << 16);
        hi[j] = (short)hb;
        lo[j] = (short)f2bf_rne(v - hf);
    }
    const size_t doff = ((size_t)(n >> 4) * KG + kg) * 128 + (size_t)(n & 15) * 8;
    *(s8v*)(b_hi + doff) = hi;
    *(s8v*)(b_lo + doff) = lo;
}

// MFMA GEMM: grid (26 m-blocks, 24 = 3 passes x 8 k-splits), 512 thr (8 waves).
// Block tile 64(M) x 384(N); wave tile 32x96 = 2x6 frags of 16x16.
// Pass 0: A_hi*B_hi, pass 1: A_lo*B_hi, pass 2: A_hi*B_lo  (~fp32-exact sum).
__global__ __launch_bounds__(512) void qkv_mfma(
    const short* __restrict__ a_hi, const short* __restrict__ a_lo,
    const short* __restrict__ b_hi, const short* __restrict__ b_lo,
    float* __restrict__ qkvp) {
    const int mb   = blockIdx.x;       // 0..25
    const int z    = blockIdx.y;       // 0..23
    const int pass = z >> 3;
    const int kc   = z & 7;            // 1024-wide K chunk -> 32 K-steps

    const short* __restrict__ A = (pass == 1) ? a_lo : a_hi;
    const short* __restrict__ Bw = (pass == 2) ? b_lo : b_hi;

    const int w    = threadIdx.x >> 6; // 0..7
    const int wm   = w & 1;            // 2 waves over M
    const int wn   = w >> 1;           // 4 waves over N
    const int l    = threadIdx.x & 63;
    const int m    = l & 15;
    const int quad = l >> 4;

    const int mt0 = mb * 4 + wm * 2;   // 2 m-frags
    const int nt0 = wn * 6;            // 6 n-frags

    f4v acc[2][6];
    #pragma unroll
    for (int i = 0; i < 2; ++i)
        #pragma unroll
        for (int j = 0; j < 6; ++j) {
            f4v zr = {0.0f, 0.0f, 0.0f, 0.0f};
            acc[i][j] = zr;
        }

    size_t aoff[2], boff[6];
    #pragma unroll
    for (int i = 0; i < 2; ++i)
        aoff[i] = ((size_t)(mt0 + i) * KG + kc * 128 + quad) * 128 + (size_t)m * 8;
    #pragma unroll
    for (int j = 0; j < 6; ++j)
        boff[j] = ((size_t)(nt0 + j) * KG + kc * 128 + quad) * 128 + (size_t)m * 8;

    for (int s = 0; s < 32; ++s) {
        const size_t soff = (size_t)s * 512;   // 4 kg per K-step * 128
        s8v af[2], bf[6];
        #pragma unroll
        for (int i = 0; i < 2; ++i) af[i] = *(const s8v*)(A + aoff[i] + soff);
        #pragma unroll
        for (int j = 0; j < 6; ++j) bf[j] = *(const s8v*)(Bw + boff[j] + soff);
        #pragma unroll
        for (int i = 0; i < 2; ++i)
            #pragma unroll
            for (int j = 0; j < 6; ++j)
                acc[i][j] = __builtin_amdgcn_mfma_f32_16x16x32_bf16(
                    af[i], bf[j], acc[i][j], 0, 0, 0);
    }

    // epilogue: C/D layout col=lane&15, row=quad*4+reg
    #pragma unroll
    for (int i = 0; i < 2; ++i) {
        #pragma unroll
        for (int j = 0; j < 6; ++j) {
            const int col = wn * 96 + j * 16 + m;
            const int row0 = mb * 64 + wm * 32 + i * 16 + quad * 4;
            if (col < NC) {
                #pragma unroll
                for (int r = 0; r < 4; ++r) {
                    const int row = row0 + r;
                    if (row < MROW)
                        atomicAdd(&qkvp[(size_t)row * NC + col], acc[i][j][r]);
                }
            }
        }
    }
}

// One block per (b,s): scores[u] = Q[s+1].K[s+u], softmax, out = sum attn_u V[s+u]
__global__ __launch_bounds__(128) void attn_kernel(
    const float* __restrict__ qkvp, float* __restrict__ out) {
    const int bs = blockIdx.x;           // 0..1599
    const int b = bs / Ss, s = bs % Ss;
    __shared__ float q[Pp], kbuf[3][Pp], vbuf[3][Pp];
    __shared__ float sc[3];
    const int tid = threadIdx.x;
    const size_t base = (size_t)(b * 102 + s) * NC;

    if (tid < Pp) {
        q[tid] = qkvp[base + NC + tid];                     // Q row s+1
        #pragma unroll
        for (int u = 0; u < 3; ++u) {
            kbuf[u][tid] = qkvp[base + (size_t)u * NC + 100 + tid];
            vbuf[u][tid] = qkvp[base + (size_t)u * NC + 200 + tid];
        }
    }
    __syncthreads();

    if (tid < 64) {
        #pragma unroll
        for (int u = 0; u < 3; ++u) {
            float ps = 0.0f;
            for (int p = tid; p < Pp; p += 64) ps += q[p] * kbuf[u][p];
            #pragma unroll
            for (int off = 32; off > 0; off >>= 1) ps += __shfl_down(ps, off);
            if (tid == 0) sc[u] = ps;
        }
    }
    __syncthreads();

    const float mx = fmaxf(sc[0], fmaxf(sc[1], sc[2]));
    const float e0 = __expf(sc[0] - mx), e1 = __expf(sc[1] - mx), e2 = __expf(sc[2] - mx);
    const float inv = 1.0f / (e0 + e1 + e2);

    if (tid < Pp) {
        out[(size_t)bs * Pp + tid] =
            inv * (e0 * vbuf[0][tid] + e1 * vbuf[1][tid] + e2 * vbuf[2][tid]);
    }
}

extern "C" void kernel_launch(void* const* d_in, const int* in_sizes, int n_in,
                              void* d_out, int out_size, void* d_ws, size_t ws_size,
                              hipStream_t stream) {
    const float* x    = (const float*)d_in[0];
    const float* wq   = (const float*)d_in[1];
    const float* wk   = (const float*)d_in[2];
    const float* wv   = (const float*)d_in[3];
    const float* fpad = (const float*)d_in[4];
    const float* bpad = (const float*)d_in[5];
    float* out = (float*)d_out;

    short* a_hi = (short*)d_ws;
    short* a_lo = a_hi + A_SEG;
    short* b_hi = a_lo + A_SEG;
    short* b_lo = b_hi + B_SEG;
    float* qkvp = (float*)(b_lo + B_SEG);   // 1632*304 fp32 ~ 2 MB; ws total ~69 MB

    const int nqkv = MROW * NC;
    zero_ws<<<(nqkv + 255) / 256, 256, 0, stream>>>(qkvp, nqkv);
    pack_a<<<dim3(A_MT, 16), 256, 0, stream>>>(x, fpad, bpad, a_hi, a_lo);
    pack_b<<<(384 * KG) / 256, 256, 0, stream>>>(wq, wk, wv, b_hi, b_lo);
    qkv_mfma<<<dim3(26, 24), 512, 0, stream>>>(a_hi, a_lo, b_hi, b_lo, qkvp);
    attn_kernel<<<Bb * Ss, 128, 0, stream>>>(qkvp, out);
}

// Round 3
// 179.935 us; speedup vs baseline: 3.4660x; 1.1125x over previous
//
#include <hip/hip_runtime.h>
#include <hip/hip_bf16.h>

// B=16, S=100, D=8192, P=100, W=3
constexpr int Dk   = 8192;
constexpr int Bb   = 16;
constexpr int Ss   = 100;
constexpr int Pp   = 100;
constexpr int MROW = 1632;     // 16 * 102 padded rows
constexpr int MPAD = 1664;     // 104 m-tiles of 16
constexpr int NT   = 20;       // n-tiles of 16 -> 320 cols (q|k|v|20 zero)
constexpr int NCC  = 320;
constexpr int KG   = 1024;     // k-groups of 8 (K=8192)

constexpr size_t B_SEG = (size_t)NT * KG * 128;   // shorts per B segment

typedef short s8v __attribute__((ext_vector_type(8)));
typedef float f4v __attribute__((ext_vector_type(4)));

__device__ inline unsigned short f2bf_rne(float f) {
    unsigned u = __float_as_uint(f);
    u += 0x7fffu + ((u >> 16) & 1u);
    return (unsigned short)(u >> 16);
}

// Pack [wq|wk|wv|0] into hi/lo fragment layout [nt][kg][lane16][8].
__global__ __launch_bounds__(256) void pack_b(
    const float* __restrict__ wq, const float* __restrict__ wk,
    const float* __restrict__ wv,
    short* __restrict__ b_hi, short* __restrict__ b_lo) {
    const int id = blockIdx.x * 256 + threadIdx.x;
    const int n  = id % NCC;
    const int kg = id / NCC;
    if (kg >= KG) return;

    const float* w = nullptr; int p = 0;
    if (n < 100)      { w = wq; p = n; }
    else if (n < 200) { w = wk; p = n - 100; }
    else if (n < 300) { w = wv; p = n - 200; }

    s8v hi, lo;
    #pragma unroll
    for (int j = 0; j < 8; ++j) {
        const float v = w ? w[(size_t)(kg * 8 + j) * Pp + p] : 0.0f;
        const unsigned u = __float_as_uint(v);
        const unsigned short hb = (unsigned short)(u >> 16);          // trunc split
        const float hf = __uint_as_float(u & 0xffff0000u);
        hi[j] = (short)hb;
        lo[j] = (short)f2bf_rne(v - hf);
    }
    const size_t doff = ((size_t)(n >> 4) * KG + kg) * 128 + (size_t)(n & 15) * 8;
    *(s8v*)(b_hi + doff) = hi;
    *(s8v*)(b_lo + doff) = lo;
}

// Fused QKV GEMM: A read fp32 straight from x/pads, hi/lo split in-register,
// 3 products (ahi*bhi + alo*bhi + ahi*blo) accumulated together.
// Grid (52 mb, 8 kc); 512 thr = 8 waves = 2 k-groups x 4 n-waves.
// Block tile 32(M) x 320(N); wave tile 32x80 (2 m-frags x 5 n-frags).
// K per block = 1024 (2 kgroups x 512); in-block LDS k-reduce, then atomicAdd.
__global__ __launch_bounds__(512) void qkv_fused(
    const float* __restrict__ x, const float* __restrict__ fpad,
    const float* __restrict__ bpad, const float* __restrict__ zrow,
    const short* __restrict__ b_hi, const short* __restrict__ b_lo,
    float* __restrict__ qkvp) {
    __shared__ float red[10240];            // 4 nw * 2 * 5 frags * 256 floats
    const int mb   = blockIdx.x;            // 0..51
    const int kc   = blockIdx.y;            // 0..7
    const int tid  = threadIdx.x;
    const int w    = tid >> 6;
    const int kg   = w & 1;
    const int nw   = w >> 1;                // 0..3
    const int l    = tid & 63;
    const int m    = l & 15;
    const int quad = l >> 4;

    // per-lane A row pointers for the 2 m-frags
    const float* rowp[2];
    #pragma unroll
    for (int i = 0; i < 2; ++i) {
        const int r = mb * 32 + i * 16 + m;
        const float* src;
        if (r >= MROW) src = zrow;                         // zero-pad tiles
        else {
            const int b = r / 102, rr = r - b * 102;
            if (rr == 0)        src = fpad + (size_t)b * Dk;
            else if (rr == 101) src = bpad + (size_t)b * Dk;
            else                src = x + ((size_t)b * Ss + (rr - 1)) * Dk;
        }
        rowp[i] = src;
    }

    const int k0  = kc * 1024 + kg * 512;
    const int nt0 = nw * 5;

    f4v acc[2][5];
    #pragma unroll
    for (int i = 0; i < 2; ++i)
        #pragma unroll
        for (int j = 0; j < 5; ++j) {
            f4v z = {0.f, 0.f, 0.f, 0.f};
            acc[i][j] = z;
        }

    const size_t bbase = ((size_t)(k0 >> 3) + quad) * 128 + (size_t)m * 8;

    for (int s = 0; s < 16; ++s) {
        const int kk = k0 + s * 32 + quad * 8;
        s8v ahi[2], alo[2];
        #pragma unroll
        for (int i = 0; i < 2; ++i) {
            const float4 v0 = *(const float4*)(rowp[i] + kk);
            const float4 v1 = *(const float4*)(rowp[i] + kk + 4);
            const float vv[8] = {v0.x, v0.y, v0.z, v0.w, v1.x, v1.y, v1.z, v1.w};
            #pragma unroll
            for (int jj = 0; jj < 8; ++jj) {
                const unsigned u = __float_as_uint(vv[jj]);
                ahi[i][jj] = (short)(unsigned short)(u >> 16);          // trunc hi
                const float hf = __uint_as_float(u & 0xffff0000u);
                alo[i][jj] = (short)f2bf_rne(vv[jj] - hf);              // rne lo
            }
        }
        const size_t bo0 = bbase + (size_t)s * 512;       // 4 kg per K-step
        #pragma unroll
        for (int j = 0; j < 5; ++j) {
            const size_t bo = bo0 + (size_t)(nt0 + j) * ((size_t)KG * 128);
            const s8v bh = *(const s8v*)(b_hi + bo);
            const s8v bl = *(const s8v*)(b_lo + bo);
            acc[0][j] = __builtin_amdgcn_mfma_f32_16x16x32_bf16(ahi[0], bh, acc[0][j], 0, 0, 0);
            acc[1][j] = __builtin_amdgcn_mfma_f32_16x16x32_bf16(ahi[1], bh, acc[1][j], 0, 0, 0);
            acc[0][j] = __builtin_amdgcn_mfma_f32_16x16x32_bf16(alo[0], bh, acc[0][j], 0, 0, 0);
            acc[1][j] = __builtin_amdgcn_mfma_f32_16x16x32_bf16(alo[1], bh, acc[1][j], 0, 0, 0);
            acc[0][j] = __builtin_amdgcn_mfma_f32_16x16x32_bf16(ahi[0], bl, acc[0][j], 0, 0, 0);
            acc[1][j] = __builtin_amdgcn_mfma_f32_16x16x32_bf16(ahi[1], bl, acc[1][j], 0, 0, 0);
        }
    }

    // in-block k-reduce: kg1 -> LDS, kg0 adds and writes
    if (kg == 1) {
        #pragma unroll
        for (int i = 0; i < 2; ++i)
            #pragma unroll
            for (int j = 0; j < 5; ++j)
                *(f4v*)&red[((((nw * 2 + i) * 5 + j) * 64) + l) * 4] = acc[i][j];
    }
    __syncthreads();
    if (kg == 0) {
        #pragma unroll
        for (int i = 0; i < 2; ++i)
            #pragma unroll
            for (int j = 0; j < 5; ++j) {
                const f4v o = *(const f4v*)&red[((((nw * 2 + i) * 5 + j) * 64) + l) * 4];
                const f4v a = acc[i][j] + o;
                const int col  = (nt0 + j) * 16 + m;
                const int row0 = mb * 32 + i * 16 + quad * 4;
                #pragma unroll
                for (int r = 0; r < 4; ++r)
                    atomicAdd(&qkvp[(size_t)(row0 + r) * NCC + col], a[r]);
            }
    }
}

// One block per (b,s): scores[u] = Q[s+1].K[s+u], softmax, out = sum attn_u V[s+u]
__global__ __launch_bounds__(128) void attn_kernel(
    const float* __restrict__ qkvp, float* __restrict__ out) {
    const int bs = blockIdx.x;           // 0..1599
    const int b = bs / Ss, s = bs % Ss;
    __shared__ float q[Pp], kbuf[3][Pp], vbuf[3][Pp];
    __shared__ float sc[3];
    const int tid = threadIdx.x;
    const size_t base = (size_t)(b * 102 + s) * NCC;

    if (tid < Pp) {
        q[tid] = qkvp[base + NCC + tid];                    // Q row s+1
        #pragma unroll
        for (int u = 0; u < 3; ++u) {
            kbuf[u][tid] = qkvp[base + (size_t)u * NCC + 100 + tid];
            vbuf[u][tid] = qkvp[base + (size_t)u * NCC + 200 + tid];
        }
    }
    __syncthreads();

    if (tid < 64) {
        #pragma unroll
        for (int u = 0; u < 3; ++u) {
            float ps = 0.0f;
            for (int p = tid; p < Pp; p += 64) ps += q[p] * kbuf[u][p];
            #pragma unroll
            for (int off = 32; off > 0; off >>= 1) ps += __shfl_down(ps, off);
            if (tid == 0) sc[u] = ps;
        }
    }
    __syncthreads();

    const float mx = fmaxf(sc[0], fmaxf(sc[1], sc[2]));
    const float e0 = __expf(sc[0] - mx), e1 = __expf(sc[1] - mx), e2 = __expf(sc[2] - mx);
    const float inv = 1.0f / (e0 + e1 + e2);

    if (tid < Pp) {
        out[(size_t)bs * Pp + tid] =
            inv * (e0 * vbuf[0][tid] + e1 * vbuf[1][tid] + e2 * vbuf[2][tid]);
    }
}

extern "C" void kernel_launch(void* const* d_in, const int* in_sizes, int n_in,
                              void* d_out, int out_size, void* d_ws, size_t ws_size,
                              hipStream_t stream) {
    const float* x    = (const float*)d_in[0];
    const float* wq   = (const float*)d_in[1];
    const float* wk   = (const float*)d_in[2];
    const float* wv   = (const float*)d_in[3];
    const float* fpad = (const float*)d_in[4];
    const float* bpad = (const float*)d_in[5];
    float* out = (float*)d_out;

    short* b_hi = (short*)d_ws;
    short* b_lo = b_hi + B_SEG;
    float* qkvp = (float*)(b_lo + B_SEG);          // 1664*320 fp32 = 2.13 MB
    float* zrow = qkvp + (size_t)MPAD * NCC;       // 8192 zero floats
    // total ws use ~12.7 MB

    hipMemsetAsync(qkvp, 0, ((size_t)MPAD * NCC + Dk) * sizeof(float), stream);
    pack_b<<<(NCC * KG) / 256, 256, 0, stream>>>(wq, wk, wv, b_hi, b_lo);
    qkv_fused<<<dim3(52, 8), 512, 0, stream>>>(x, fpad, bpad, zrow, b_hi, b_lo, qkvp);
    attn_kernel<<<Bb * Ss, 128, 0, stream>>>(qkvp, out);
}

// Round 4
// 172.056 us; speedup vs baseline: 3.6247x; 1.0458x over previous
//
#include <hip/hip_runtime.h>
#include <hip/hip_bf16.h>

// B=16, S=100, D=8192, P=100, W=3
constexpr int Dk   = 8192;
constexpr int Bb   = 16;
constexpr int Ss   = 100;
constexpr int Pp   = 100;
constexpr int MROW = 1632;     // 16 * 102 padded rows
constexpr int MPAD = 1664;     // 26 m-blocks of 64
constexpr int NT   = 20;       // n-tiles of 16 -> 320 cols (q|k|v|20 zero)
constexpr int NCC  = 320;
constexpr int KG   = 1024;     // k-groups of 8 (K=8192)
constexpr int KC   = 16;       // K splits (chunk 512)
constexpr int CH   = 10;       // attn positions per block

constexpr size_t B_SEG    = (size_t)NT * KG * 128;      // shorts per B segment
constexpr size_t PSTRIDE  = (size_t)MPAD * NCC;         // floats per part slice

typedef short s8v __attribute__((ext_vector_type(8)));
typedef float f4v __attribute__((ext_vector_type(4)));

__device__ inline unsigned short f2bf_rne(float f) {
    unsigned u = __float_as_uint(f);
    u += 0x7fffu + ((u >> 16) & 1u);
    return (unsigned short)(u >> 16);
}

// Pack [wq|wk|wv|0] into hi/lo fragment layout [nt][kg][lane16][8].
__global__ __launch_bounds__(256) void pack_b(
    const float* __restrict__ wq, const float* __restrict__ wk,
    const float* __restrict__ wv,
    short* __restrict__ b_hi, short* __restrict__ b_lo) {
    const int id = blockIdx.x * 256 + threadIdx.x;
    const int n  = id % NCC;
    const int kg = id / NCC;
    if (kg >= KG) return;

    const float* w = nullptr; int p = 0;
    if (n < 100)      { w = wq; p = n; }
    else if (n < 200) { w = wk; p = n - 100; }
    else if (n < 300) { w = wv; p = n - 200; }

    s8v hi, lo;
    #pragma unroll
    for (int j = 0; j < 8; ++j) {
        const float v = w ? w[(size_t)(kg * 8 + j) * Pp + p] : 0.0f;
        const unsigned u = __float_as_uint(v);
        hi[j] = (short)(unsigned short)(u >> 16);                 // trunc split
        const float hf = __uint_as_float(u & 0xffff0000u);
        lo[j] = (short)f2bf_rne(v - hf);
    }
    const size_t doff = ((size_t)(n >> 4) * KG + kg) * 128 + (size_t)(n & 15) * 8;
    *(s8v*)(b_hi + doff) = hi;
    *(s8v*)(b_lo + doff) = lo;
}

// Fused QKV GEMM, register-double-buffered.
// Grid (26 mb, 16 kc); 512 thr = 8 waves = 2 mw x 4 nw.
// Block tile 64(M) x 320(N); wave tile 32x80 (2 m-frags x 5 n-frags).
// K-chunk 512 = 16 K-steps of 32. Plain stores to part[kc] (no atomics).
__global__ __launch_bounds__(512) void qkv_fused(
    const float* __restrict__ x, const float* __restrict__ fpad,
    const float* __restrict__ bpad,
    const short* __restrict__ b_hi, const short* __restrict__ b_lo,
    float* __restrict__ part) {
    const int mb   = blockIdx.x;         // 0..25
    const int kc   = blockIdx.y;         // 0..15
    const int tid  = threadIdx.x;
    const int w    = tid >> 6;
    const int mw   = w & 1;
    const int nw   = w >> 1;             // 0..3
    const int l    = tid & 63;
    const int m    = l & 15;
    const int quad = l >> 4;

    // per-lane A row pointers for the 2 m-frags
    const float* rowp[2];
    #pragma unroll
    for (int i = 0; i < 2; ++i) {
        const int r = mb * 64 + mw * 32 + i * 16 + m;
        const float* src;
        if (r >= MROW) src = fpad;        // junk rows, never read downstream
        else {
            const int b = r / 102, rr = r - b * 102;
            if (rr == 0)        src = fpad + (size_t)b * Dk;
            else if (rr == 101) src = bpad + (size_t)b * Dk;
            else                src = x + ((size_t)b * Ss + (rr - 1)) * Dk;
        }
        rowp[i] = src;
    }

    const int k0  = kc * 512;
    const int nt0 = nw * 5;
    const size_t bbase = ((size_t)(k0 >> 3) + quad) * 128 + (size_t)m * 8;

    f4v acc[2][5];
    #pragma unroll
    for (int i = 0; i < 2; ++i)
        #pragma unroll
        for (int j = 0; j < 5; ++j) {
            f4v z = {0.f, 0.f, 0.f, 0.f};
            acc[i][j] = z;
        }

    // ping-pong register buffers
    float4 av[2][2][2];
    s8v bh[2][5], bl[2][5];

    auto loadstep = [&](int s, int buf) {
        const int kk = k0 + s * 32 + quad * 8;
        #pragma unroll
        for (int i = 0; i < 2; ++i) {
            av[buf][i][0] = *(const float4*)(rowp[i] + kk);
            av[buf][i][1] = *(const float4*)(rowp[i] + kk + 4);
        }
        const size_t bo0 = bbase + (size_t)s * 512;
        #pragma unroll
        for (int j = 0; j < 5; ++j) {
            const size_t bo = bo0 + (size_t)(nt0 + j) * ((size_t)KG * 128);
            bh[buf][j] = *(const s8v*)(b_hi + bo);
            bl[buf][j] = *(const s8v*)(b_lo + bo);
        }
    };

    loadstep(0, 0);

    #pragma unroll
    for (int s = 0; s < 16; ++s) {
        const int cur = s & 1, nxt = cur ^ 1;
        if (s < 15) loadstep(s + 1, nxt);

        // convert current A to hi/lo bf16
        s8v ahi[2], alo[2];
        #pragma unroll
        for (int i = 0; i < 2; ++i) {
            const float4 v0 = av[cur][i][0], v1 = av[cur][i][1];
            const float vv[8] = {v0.x, v0.y, v0.z, v0.w, v1.x, v1.y, v1.z, v1.w};
            #pragma unroll
            for (int jj = 0; jj < 8; ++jj) {
                const unsigned u = __float_as_uint(vv[jj]);
                ahi[i][jj] = (short)(unsigned short)(u >> 16);
                const float hf = __uint_as_float(u & 0xffff0000u);
                alo[i][jj] = (short)f2bf_rne(vv[jj] - hf);
            }
        }
        #pragma unroll
        for (int j = 0; j < 5; ++j) {
            const s8v bhv = bh[cur][j], blv = bl[cur][j];
            acc[0][j] = __builtin_amdgcn_mfma_f32_16x16x32_bf16(ahi[0], bhv, acc[0][j], 0, 0, 0);
            acc[1][j] = __builtin_amdgcn_mfma_f32_16x16x32_bf16(ahi[1], bhv, acc[1][j], 0, 0, 0);
            acc[0][j] = __builtin_amdgcn_mfma_f32_16x16x32_bf16(alo[0], bhv, acc[0][j], 0, 0, 0);
            acc[1][j] = __builtin_amdgcn_mfma_f32_16x16x32_bf16(alo[1], bhv, acc[1][j], 0, 0, 0);
            acc[0][j] = __builtin_amdgcn_mfma_f32_16x16x32_bf16(ahi[0], blv, acc[0][j], 0, 0, 0);
            acc[1][j] = __builtin_amdgcn_mfma_f32_16x16x32_bf16(ahi[1], blv, acc[1][j], 0, 0, 0);
        }
    }

    // plain stores: each (kc,row,col) owned by exactly one lane
    float* __restrict__ pout = part + (size_t)kc * PSTRIDE;
    #pragma unroll
    for (int i = 0; i < 2; ++i) {
        #pragma unroll
        for (int j = 0; j < 5; ++j) {
            const int col  = (nt0 + j) * 16 + m;
            const int row0 = mb * 64 + mw * 32 + i * 16 + quad * 4;
            #pragma unroll
            for (int r = 0; r < 4; ++r)
                pout[(size_t)(row0 + r) * NCC + col] = acc[i][j][r];
        }
    }
}

// Chunked attention + k-split reduction.
// Block = (b, chunk of 10 positions); grid 160, 256 thr.
__global__ __launch_bounds__(256) void attn2(
    const float* __restrict__ part, float* __restrict__ out) {
    const int blk = blockIdx.x;          // 0..159
    const int b  = blk / (Ss / CH);
    const int c  = blk % (Ss / CH);
    const int s0 = c * CH;
    const int tid = threadIdx.x;

    __shared__ float red[CH + 2][305];   // rows s0 .. s0+11, cols 0..299
    __shared__ float sc[CH][3];

    // reduce 16 partials into LDS
    for (int idx = tid; idx < (CH + 2) * 300; idx += 256) {
        const int row = idx / 300, col = idx % 300;
        const size_t base = (size_t)(b * 102 + s0 + row) * NCC + col;
        float sum = 0.0f;
        #pragma unroll
        for (int k = 0; k < KC; ++k) sum += part[(size_t)k * PSTRIDE + base];
        red[row][col] = sum;
    }
    __syncthreads();

    // 30 score dots: (ss, u): Q[ss+1] . K[ss+u]
    if (tid < CH * 3) {
        const int ss = tid / 3, u = tid % 3;
        float d = 0.0f;
        #pragma unroll 4
        for (int p = 0; p < Pp; ++p) d += red[ss + 1][p] * red[ss + u][100 + p];
        sc[ss][u] = d;
    }
    __syncthreads();

    // outputs: softmax over 3, weighted V sum
    for (int idx = tid; idx < CH * Pp; idx += 256) {
        const int ss = idx / Pp, p = idx % Pp;
        const float a0 = sc[ss][0], a1 = sc[ss][1], a2 = sc[ss][2];
        const float mx = fmaxf(a0, fmaxf(a1, a2));
        const float e0 = __expf(a0 - mx), e1 = __expf(a1 - mx), e2 = __expf(a2 - mx);
        const float inv = 1.0f / (e0 + e1 + e2);
        out[(size_t)(b * Ss + s0 + ss) * Pp + p] =
            inv * (e0 * red[ss][200 + p] + e1 * red[ss + 1][200 + p] +
                   e2 * red[ss + 2][200 + p]);
    }
}

extern "C" void kernel_launch(void* const* d_in, const int* in_sizes, int n_in,
                              void* d_out, int out_size, void* d_ws, size_t ws_size,
                              hipStream_t stream) {
    const float* x    = (const float*)d_in[0];
    const float* wq   = (const float*)d_in[1];
    const float* wk   = (const float*)d_in[2];
    const float* wv   = (const float*)d_in[3];
    const float* fpad = (const float*)d_in[4];
    const float* bpad = (const float*)d_in[5];
    float* out = (float*)d_out;

    short* b_hi = (short*)d_ws;
    short* b_lo = b_hi + B_SEG;
    float* part = (float*)(b_lo + B_SEG);   // 16 * 1664 * 320 fp32 = 34.1 MB
    // total ws use ~44.6 MB; no zeroing needed (part fully overwritten)

    pack_b<<<(NCC * KG) / 256, 256, 0, stream>>>(wq, wk, wv, b_hi, b_lo);
    qkv_fused<<<dim3(26, KC), 512, 0, stream>>>(x, fpad, bpad, b_hi, b_lo, part);
    attn2<<<Bb * (Ss / CH), 256, 0, stream>>>(part, out);
}

// Round 5
// 155.380 us; speedup vs baseline: 4.0137x; 1.1073x over previous
//
#include <hip/hip_runtime.h>
#include <hip/hip_bf16.h>

// B=16, S=100, D=8192, P=100, W=3
constexpr int Dk   = 8192;
constexpr int Bb   = 16;
constexpr int Ss   = 100;
constexpr int Pp   = 100;
constexpr int MROW = 1632;     // 16 * 102 padded rows
constexpr int MPAD = 1664;     // 52 m-blocks of 32
constexpr int NT   = 20;       // n-tiles of 16 -> 320 cols (q|k|v|20 zero)
constexpr int NCC  = 320;
constexpr int KG   = 1024;     // k-groups of 8 (K=8192)
constexpr int KC   = 32;       // K splits (chunk 256)
constexpr int CH   = 5;        // attn positions per block

constexpr size_t B_SEG   = (size_t)NT * KG * 128;     // shorts per B segment
constexpr size_t PSTRIDE = (size_t)MPAD * NCC;        // elems per part slice (bf16)

typedef short s8v __attribute__((ext_vector_type(8)));
typedef short s4v __attribute__((ext_vector_type(4)));
typedef float f4v __attribute__((ext_vector_type(4)));

__device__ inline unsigned short f2bf_rne(float f) {
    unsigned u = __float_as_uint(f);
    u += 0x7fffu + ((u >> 16) & 1u);
    return (unsigned short)(u >> 16);
}

// Pack [wq|wk|wv|0] into hi/lo fragment layout [nt][kg][lane16][8].
__global__ __launch_bounds__(256) void pack_b(
    const float* __restrict__ wq, const float* __restrict__ wk,
    const float* __restrict__ wv,
    short* __restrict__ b_hi, short* __restrict__ b_lo) {
    const int id = blockIdx.x * 256 + threadIdx.x;
    const int n  = id % NCC;
    const int kg = id / NCC;
    if (kg >= KG) return;

    const float* w = nullptr; int p = 0;
    if (n < 100)      { w = wq; p = n; }
    else if (n < 200) { w = wk; p = n - 100; }
    else if (n < 300) { w = wv; p = n - 200; }

    s8v hi, lo;
    #pragma unroll
    for (int j = 0; j < 8; ++j) {
        const float v = w ? w[(size_t)(kg * 8 + j) * Pp + p] : 0.0f;
        const unsigned u = __float_as_uint(v);
        hi[j] = (short)(unsigned short)(u >> 16);                 // trunc split
        const float hf = __uint_as_float(u & 0xffff0000u);
        lo[j] = (short)f2bf_rne(v - hf);
    }
    const size_t doff = ((size_t)(n >> 4) * KG + kg) * 128 + (size_t)(n & 15) * 8;
    *(s8v*)(b_hi + doff) = hi;
    *(s8v*)(b_lo + doff) = lo;
}

// Fused QKV GEMM, LDS-staged A with once-per-block hi/lo conversion.
// Grid (52 mb, 32 kc); 256 thr = 4 waves, all split over N.
// Block tile 32(M) x 320(N); wave tile 32x80 (2 m-frags x 5 n-frags).
// K-chunk 256 = 8 K-steps of 32. Stores bf16 partials to part[kc].
__global__ __launch_bounds__(256) void qkv_fused(
    const float* __restrict__ x, const float* __restrict__ fpad,
    const float* __restrict__ bpad,
    const short* __restrict__ b_hi, const short* __restrict__ b_lo,
    unsigned short* __restrict__ part) {
    __shared__ __align__(16) short ahis[1024];   // [frag2][kg4][lane16][8]
    __shared__ __align__(16) short alos[1024];

    const int mb   = blockIdx.x;         // 0..51
    const int kc   = blockIdx.y;         // 0..31
    const int tid  = threadIdx.x;
    const int w    = tid >> 6;           // nw 0..3
    const int l    = tid & 63;
    const int m    = l & 15;
    const int quad = l >> 4;

    // staging role: thread -> (row sr, k-offset skq*4)
    const int sr  = tid >> 3;            // 0..31
    const int skq = tid & 7;             // 0..7
    const float* srow;
    {
        const int r = mb * 32 + sr;
        if (r >= MROW) srow = fpad;      // junk rows, never read downstream
        else {
            const int b = r / 102, rr = r - b * 102;
            if (rr == 0)        srow = fpad + (size_t)b * Dk;
            else if (rr == 101) srow = bpad + (size_t)b * Dk;
            else                srow = x + ((size_t)b * Ss + (rr - 1)) * Dk;
        }
    }
    const int woff = ((sr >> 4) * 4 + (skq >> 1)) * 128 + (sr & 15) * 8 + (skq & 1) * 4;

    f4v acc[2][5];
    #pragma unroll
    for (int i = 0; i < 2; ++i)
        #pragma unroll
        for (int j = 0; j < 5; ++j) {
            f4v z = {0.f, 0.f, 0.f, 0.f};
            acc[i][j] = z;
        }

    for (int s = 0; s < 8; ++s) {
        // ---- stage A: fp32 load -> hi/lo bf16 -> LDS fragment layout ----
        const float4 v = *(const float4*)(srow + kc * 256 + s * 32 + skq * 4);
        const float vv[4] = {v.x, v.y, v.z, v.w};
        s4v hi4, lo4;
        #pragma unroll
        for (int jj = 0; jj < 4; ++jj) {
            const unsigned u = __float_as_uint(vv[jj]);
            hi4[jj] = (short)(unsigned short)(u >> 16);
            const float hf = __uint_as_float(u & 0xffff0000u);
            lo4[jj] = (short)f2bf_rne(vv[jj] - hf);
        }
        __syncthreads();                 // prev step's reads complete
        *(s4v*)&ahis[woff] = hi4;
        *(s4v*)&alos[woff] = lo4;
        __syncthreads();                 // staged data visible

        // ---- A fragments from LDS (conflict-free b128) ----
        const s8v ah0 = *(const s8v*)&ahis[(quad * 16 + m) * 8];
        const s8v ah1 = *(const s8v*)&ahis[((4 + quad) * 16 + m) * 8];
        const s8v al0 = *(const s8v*)&alos[(quad * 16 + m) * 8];
        const s8v al1 = *(const s8v*)&alos[((4 + quad) * 16 + m) * 8];

        // ---- B from global (L2-resident packed), 30 MFMAs ----
        const int kgg = kc * 32 + s * 4 + quad;
        #pragma unroll
        for (int j = 0; j < 5; ++j) {
            const size_t bo = ((size_t)(w * 5 + j) * KG + kgg) * 128 + (size_t)m * 8;
            const s8v bh = *(const s8v*)(b_hi + bo);
            const s8v bl = *(const s8v*)(b_lo + bo);
            acc[0][j] = __builtin_amdgcn_mfma_f32_16x16x32_bf16(ah0, bh, acc[0][j], 0, 0, 0);
            acc[1][j] = __builtin_amdgcn_mfma_f32_16x16x32_bf16(ah1, bh, acc[1][j], 0, 0, 0);
            acc[0][j] = __builtin_amdgcn_mfma_f32_16x16x32_bf16(al0, bh, acc[0][j], 0, 0, 0);
            acc[1][j] = __builtin_amdgcn_mfma_f32_16x16x32_bf16(al1, bh, acc[1][j], 0, 0, 0);
            acc[0][j] = __builtin_amdgcn_mfma_f32_16x16x32_bf16(ah0, bl, acc[0][j], 0, 0, 0);
            acc[1][j] = __builtin_amdgcn_mfma_f32_16x16x32_bf16(ah1, bl, acc[1][j], 0, 0, 0);
        }
    }

    // ---- store bf16 partials (each (kc,row,col) owned by one lane) ----
    unsigned short* __restrict__ pout = part + (size_t)kc * PSTRIDE;
    #pragma unroll
    for (int i = 0; i < 2; ++i) {
        #pragma unroll
        for (int j = 0; j < 5; ++j) {
            const int col  = (w * 5 + j) * 16 + m;
            const int row0 = mb * 32 + i * 16 + quad * 4;
            #pragma unroll
            for (int r = 0; r < 4; ++r)
                pout[(size_t)(row0 + r) * NCC + col] = f2bf_rne(acc[i][j][r]);
        }
    }
}

// Attention + k-split reduction. Block = (b, chunk of 5 positions); grid 320.
__global__ __launch_bounds__(256) void attn3(
    const unsigned short* __restrict__ part, float* __restrict__ out) {
    const int blk = blockIdx.x;          // 0..319
    const int b  = blk / (Ss / CH);
    const int c  = blk % (Ss / CH);
    const int s0 = c * CH;
    const int tid = threadIdx.x;

    __shared__ float red[CH + 2][304];   // rows s0..s0+6, cols 0..299
    __shared__ float sc[CH][3];

    // reduce KC bf16 partials into LDS (coalesced per k-slice)
    for (int idx = tid; idx < (CH + 2) * 300; idx += 256) {
        const int row = idx / 300, col = idx % 300;
        const size_t base = (size_t)(b * 102 + s0 + row) * NCC + col;
        float sum = 0.0f;
        #pragma unroll
        for (int k = 0; k < KC; ++k)
            sum += __uint_as_float((unsigned)part[(size_t)k * PSTRIDE + base] << 16);
        red[row][col] = sum;
    }
    __syncthreads();

    // 15 score dots, one per 16-lane group: (ss,u): Q[ss+1].K[ss+u]
    if (tid < CH * 3 * 16) {
        const int d = tid >> 4, g = tid & 15;
        const int ss = d / 3, u = d % 3;
        float ps = 0.0f;
        #pragma unroll
        for (int t = 0; t < 7; ++t) {
            const int p = g + t * 16;
            if (p < Pp) ps += red[ss + 1][p] * red[ss + u][100 + p];
        }
        #pragma unroll
        for (int off = 8; off > 0; off >>= 1) ps += __shfl_down(ps, off, 16);
        if (g == 0) sc[ss][u] = ps;
    }
    __syncthreads();

    // outputs: softmax over 3, weighted V sum
    for (int idx = tid; idx < CH * Pp; idx += 256) {
        const int ss = idx / Pp, p = idx % Pp;
        const float a0 = sc[ss][0], a1 = sc[ss][1], a2 = sc[ss][2];
        const float mx = fmaxf(a0, fmaxf(a1, a2));
        const float e0 = __expf(a0 - mx), e1 = __expf(a1 - mx), e2 = __expf(a2 - mx);
        const float inv = 1.0f / (e0 + e1 + e2);
        out[(size_t)(b * Ss + s0 + ss) * Pp + p] =
            inv * (e0 * red[ss][200 + p] + e1 * red[ss + 1][200 + p] +
                   e2 * red[ss + 2][200 + p]);
    }
}

extern "C" void kernel_launch(void* const* d_in, const int* in_sizes, int n_in,
                              void* d_out, int out_size, void* d_ws, size_t ws_size,
                              hipStream_t stream) {
    const float* x    = (const float*)d_in[0];
    const float* wq   = (const float*)d_in[1];
    const float* wk   = (const float*)d_in[2];
    const float* wv   = (const float*)d_in[3];
    const float* fpad = (const float*)d_in[4];
    const float* bpad = (const float*)d_in[5];
    float* out = (float*)d_out;

    short* b_hi = (short*)d_ws;
    short* b_lo = b_hi + B_SEG;
    unsigned short* part = (unsigned short*)(b_lo + B_SEG);  // 32*1664*320 bf16 = 34.1 MB
    // total ws ~44.6 MB; part fully overwritten, no zeroing needed

    pack_b<<<(NCC * KG) / 256, 256, 0, stream>>>(wq, wk, wv, b_hi, b_lo);
    qkv_fused<<<dim3(52, KC), 256, 0, stream>>>(x, fpad, bpad, b_hi, b_lo, part);
    attn3<<<Bb * (Ss / CH), 256, 0, stream>>>(part, out);
}